// Round 1
// baseline (112.350 us; speedup 1.0000x reference)
//
#include <hip/hip_runtime.h>
#include <math.h>

#define NB     8
#define NPTS   32768
#define KPRIM  128
#define NSKEL  2048
#define NCTRL  4
#define NT     16
#define NCURVE (KPRIM * NT)          // 2048 curve points per batch
#define TOTAL_OCC (NB * NPTS)        // 262144 rows (B*Np)

// workspace layout (in floats)
//  [0..15]                      accumulators: 0=recon_sum, 1=overlap_sum
//  [16 .. 16+NB*NCURVE*4)       curves as float4 (xyz + pad)
//  next NB*NSKEL*4              minA partial (per skeleton point, 4 chunks)
//  next NB*NCURVE*4             minB partial (per curve point, 4 chunks)
#define WS_ACC    0
#define WS_CURVES 16
#define WS_MINA   (WS_CURVES + NB * NCURVE * 4)
#define WS_MINB   (WS_MINA   + NB * NSKEL * 4)

// ---------------- curves: (B,K,T,3) = basis(16x4) @ (ctrl*w) ----------------
__global__ void curves_kernel(const float* __restrict__ prim,
                              const float* __restrict__ w,
                              const float* __restrict__ basis,
                              float* __restrict__ curves) {
    int idx = blockIdx.x * blockDim.x + threadIdx.x;   // over NB*KPRIM*NT*4
    if (idx >= NB * KPRIM * NT * 4) return;
    int d    = idx & 3;
    int rest = idx >> 2;          // b*K*T + ...
    int t    = rest % NT;
    int bk   = rest / NT;         // b*KPRIM + k
    float v = 0.0f;
    if (d < 3) {
        float ww = w[bk];
        const float* p  = prim + bk * 16;
        const float* bs = basis + t * NCTRL;
        v = ww * (bs[0] * p[0 * 3 + d] + bs[1] * p[1 * 3 + d] +
                  bs[2] * p[2 * 3 + d] + bs[3] * p[3 * 3 + d]);
    }
    int b = bk / KPRIM;
    int k = bk % KPRIM;
    curves[(size_t)(b * NCURVE + k * NT + t) * 4 + d] = v;
}

// ---------------- recon: mean((pred-gt)^2) ----------------
__global__ void recon_kernel(const float4* __restrict__ pred,
                             const float4* __restrict__ gt,
                             float* __restrict__ acc) {
    int idx = blockIdx.x * blockDim.x + threadIdx.x;   // over TOTAL_OCC/4
    float4 p = pred[idx];
    float4 g = gt[idx];
    float dx = p.x - g.x, dy = p.y - g.y, dz = p.z - g.z, dw = p.w - g.w;
    float s = dx * dx + dy * dy + dz * dz + dw * dw;

    __shared__ float red[256];
    int t = threadIdx.x;
    red[t] = s; __syncthreads();
    for (int st = 128; st > 0; st >>= 1) {
        if (t < st) red[t] += red[t + st];
        __syncthreads();
    }
    if (t == 0) atomicAdd(&acc[0], red[0]);
}

// ---------------- overlap: per-row masked sum, penalty ----------------
// block handles 64 rows (= 2048 float4 contiguous). 32-lane subgroup = 1 row.
__global__ void overlap_kernel(const float4* __restrict__ occ,
                               float* __restrict__ acc) {
    int t = threadIdx.x;
    size_t base = (size_t)blockIdx.x * 2048;
    float pen = 0.0f;
#pragma unroll
    for (int i = 0; i < 8; ++i) {
        int j = i * 256 + t;
        float4 v = occ[base + j];
        float s = (v.x > 0.5f ? v.x : 0.0f) + (v.y > 0.5f ? v.y : 0.0f) +
                  (v.z > 0.5f ? v.z : 0.0f) + (v.w > 0.5f ? v.w : 0.0f);
        // reduce across the 32 lanes that own this row
        s += __shfl_xor(s, 1);
        s += __shfl_xor(s, 2);
        s += __shfl_xor(s, 4);
        s += __shfl_xor(s, 8);
        s += __shfl_xor(s, 16);
        if ((t & 31) == 0) pen += fmaxf(s - 32.0f, 0.0f);
    }
    __shared__ float red[256];
    red[t] = pen; __syncthreads();
    for (int st = 128; st > 0; st >>= 1) {
        if (t < st) red[t] += red[t + st];
        __syncthreads();
    }
    if (t == 0) atomicAdd(&acc[1], red[0]);
}

// ---------------- chamfer A: per skeleton point, min d2 over curve chunk ----
__global__ void chamferA_kernel(const float* __restrict__ skel,
                                const float4* __restrict__ curves,
                                float* __restrict__ minA) {
    int bx = blockIdx.x;            // b*32 + nb*4 + mc
    int b  = bx >> 5;
    int rm = bx & 31;
    int nb = rm >> 2;
    int mc = rm & 3;

    __shared__ float4 cp[512];
    const float4* csrc = curves + (size_t)b * NCURVE + mc * 512;
    cp[threadIdx.x]       = csrc[threadIdx.x];
    cp[threadIdx.x + 256] = csrc[threadIdx.x + 256];
    __syncthreads();

    int n = nb * 256 + threadIdx.x;
    const float* s = skel + ((size_t)b * NSKEL + n) * 3;
    float ax = s[0], ay = s[1], az = s[2];

    float m0 = 3.4e38f, m1 = 3.4e38f, m2 = 3.4e38f, m3 = 3.4e38f;
    for (int m = 0; m < 512; m += 4) {
        float4 c0 = cp[m], c1 = cp[m + 1], c2 = cp[m + 2], c3 = cp[m + 3];
        float dx, dy, dz;
        dx = ax - c0.x; dy = ay - c0.y; dz = az - c0.z;
        m0 = fminf(m0, fmaf(dz, dz, fmaf(dy, dy, dx * dx)));
        dx = ax - c1.x; dy = ay - c1.y; dz = az - c1.z;
        m1 = fminf(m1, fmaf(dz, dz, fmaf(dy, dy, dx * dx)));
        dx = ax - c2.x; dy = ay - c2.y; dz = az - c2.z;
        m2 = fminf(m2, fmaf(dz, dz, fmaf(dy, dy, dx * dx)));
        dx = ax - c3.x; dy = ay - c3.y; dz = az - c3.z;
        m3 = fminf(m3, fmaf(dz, dz, fmaf(dy, dy, dx * dx)));
    }
    float md = fminf(fminf(m0, m1), fminf(m2, m3));
    minA[((size_t)b * NSKEL + n) * 4 + mc] = md;
}

// ---------------- chamfer B: per curve point, min d2 over skeleton chunk ----
__global__ void chamferB_kernel(const float* __restrict__ skel,
                                const float4* __restrict__ curves,
                                float* __restrict__ minB) {
    int bx = blockIdx.x;
    int b  = bx >> 5;
    int rm = bx & 31;
    int nb = rm >> 2;
    int mc = rm & 3;

    __shared__ float4 sp[512];
    float* sf = (float*)sp;
    const float* ssrc = skel + (size_t)b * NSKEL * 3 + (size_t)mc * 512 * 3;
    for (int i = threadIdx.x; i < 1536; i += 256) {
        int p = i / 3, c = i % 3;
        sf[p * 4 + c] = ssrc[i];
    }
    __syncthreads();

    int m = nb * 256 + threadIdx.x;
    float4 cpt = curves[(size_t)b * NCURVE + m];
    float ax = cpt.x, ay = cpt.y, az = cpt.z;

    float m0 = 3.4e38f, m1 = 3.4e38f, m2 = 3.4e38f, m3 = 3.4e38f;
    for (int n = 0; n < 512; n += 4) {
        float4 c0 = sp[n], c1 = sp[n + 1], c2 = sp[n + 2], c3 = sp[n + 3];
        float dx, dy, dz;
        dx = ax - c0.x; dy = ay - c0.y; dz = az - c0.z;
        m0 = fminf(m0, fmaf(dz, dz, fmaf(dy, dy, dx * dx)));
        dx = ax - c1.x; dy = ay - c1.y; dz = az - c1.z;
        m1 = fminf(m1, fmaf(dz, dz, fmaf(dy, dy, dx * dx)));
        dx = ax - c2.x; dy = ay - c2.y; dz = az - c2.z;
        m2 = fminf(m2, fmaf(dz, dz, fmaf(dy, dy, dx * dx)));
        dx = ax - c3.x; dy = ay - c3.y; dz = az - c3.z;
        m3 = fminf(m3, fmaf(dz, dz, fmaf(dy, dy, dx * dx)));
    }
    float md = fminf(fminf(m0, m1), fminf(m2, m3));
    minB[((size_t)b * NCURVE + m) * 4 + mc] = md;
}

// ---------------- finalize: one block per batch ----------------
__device__ inline float blk_reduce(float v, float* red) {
    int t = threadIdx.x;
    __syncthreads();
    red[t] = v; __syncthreads();
    for (int st = 128; st > 0; st >>= 1) {
        if (t < st) red[t] += red[t + st];
        __syncthreads();
    }
    return red[0];
}

__global__ void finalize_kernel(const float* __restrict__ wts,
                                const float* __restrict__ acc,
                                const float* __restrict__ minA,
                                const float* __restrict__ minB,
                                float* __restrict__ out) {
    int b = blockIdx.x;
    int t = threadIdx.x;
    float ca = 0.0f, cb = 0.0f, ps = 0.0f;
    for (int i = t; i < NSKEL; i += 256) {
        const float* q = minA + ((size_t)b * NSKEL + i) * 4;
        ca += sqrtf(fminf(fminf(q[0], q[1]), fminf(q[2], q[3])));
    }
    for (int i = t; i < NCURVE; i += 256) {
        const float* q = minB + ((size_t)b * NCURVE + i) * 4;
        cb += sqrtf(fminf(fminf(q[0], q[1]), fminf(q[2], q[3])));
    }
    for (int i = t; i < NB * KPRIM; i += 256) {
        float x = wts[i];
        ps += 1.0f / (1.0f + expf(-x));
    }
    __shared__ float red[256];
    float ca_s = blk_reduce(ca, red);
    float cb_s = blk_reduce(cb, red);
    float ps_s = blk_reduce(ps, red);
    if (t == 0) {
        float recon = acc[0] / (float)TOTAL_OCC;
        float overl = 0.1f * acc[1] / (float)TOTAL_OCC;
        float pars  = 0.1f * sqrtf(ps_s);
        out[b] = recon + overl + pars + ca_s / (float)NSKEL + cb_s / (float)NCURVE;
    }
}

extern "C" void kernel_launch(void* const* d_in, const int* in_sizes, int n_in,
                              void* d_out, int out_size, void* d_ws, size_t ws_size,
                              hipStream_t stream) {
    const float* pred  = (const float*)d_in[0];
    const float* gt    = (const float*)d_in[1];
    const float* occ   = (const float*)d_in[2];
    const float* prim  = (const float*)d_in[3];
    const float* wts   = (const float*)d_in[4];
    const float* skel  = (const float*)d_in[5];
    const float* basis = (const float*)d_in[6];
    float* out = (float*)d_out;
    float* ws  = (float*)d_ws;

    float* acc    = ws + WS_ACC;
    float* curves = ws + WS_CURVES;
    float* minA   = ws + WS_MINA;
    float* minB   = ws + WS_MINB;

    hipMemsetAsync(acc, 0, 16 * sizeof(float), stream);

    curves_kernel<<<(NB * KPRIM * NT * 4) / 256, 256, 0, stream>>>(prim, wts, basis, curves);
    recon_kernel<<<(TOTAL_OCC / 4) / 256, 256, 0, stream>>>(
        (const float4*)pred, (const float4*)gt, acc);
    overlap_kernel<<<TOTAL_OCC / 64, 256, 0, stream>>>((const float4*)occ, acc);
    chamferA_kernel<<<NB * 8 * 4, 256, 0, stream>>>(skel, (const float4*)curves, minA);
    chamferB_kernel<<<NB * 8 * 4, 256, 0, stream>>>(skel, (const float4*)curves, minB);
    finalize_kernel<<<NB, 256, 0, stream>>>(wts, acc, minA, minB, out);
}